// Round 14
// baseline (99.686 us; speedup 1.0000x reference)
//
#include <hip/hip_runtime.h>

// ---------------------------------------------------------------------------
// MultiHeadAttentionWindow: B=8 K=4000 D=256 H=8 DQ=DV=32 WIN=200 PAD=50 STEP=100
// Pipeline (4 launches): prep_weights; proj_gemm (merged q/k/v, grid.y=mode);
//   attn_win (chunked-E); out_gemm.
// Round-14: A-panel staged WHOLE and CONTIGUOUSLY (64 rows x 1KB = 64KB
//   sequential per block) at kernel entry -> DRAM-friendly streaming; K-loop
//   stages only B (2-phase dbuf global_load_lds, counted vmcnt). Theory: all
//   r7-r13 variants (67-86us) shared per-iter 128B/row scattered A reads ->
//   1.5-2.3 TB/s DRAM efficiency cap; out_gemm (L2-hot A) is ~4-6us with the
//   same loop. fill_edges eliminated: left-pad replicated by t==0 epilogue
//   threads; zero-tails dropped (causally masked to exact 0, garbage-safe).
// ---------------------------------------------------------------------------

typedef __bf16 bf16_t;
typedef __bf16 bf16x4 __attribute__((ext_vector_type(4)));
typedef __bf16 bf16x8 __attribute__((ext_vector_type(8)));
typedef float  f32x4  __attribute__((ext_vector_type(4)));

#define MFMA16(a, b, c) __builtin_amdgcn_mfma_f32_16x16x32_bf16((a), (b), (c), 0, 0, 0)

typedef __attribute__((address_space(1))) const unsigned char gas_u8;
typedef __attribute__((address_space(3))) unsigned char las_u8;

static __device__ __forceinline__ void gload16(const void* g, void* l) {
  __builtin_amdgcn_global_load_lds((gas_u8*)g, (las_u8*)l, 16, 0, 0);
}

static __device__ __forceinline__ bf16x4 cvt4(float4 a) {
  bf16x4 r;
  r[0] = (bf16_t)a.x; r[1] = (bf16_t)a.y; r[2] = (bf16_t)a.z; r[3] = (bf16_t)a.w;
  return r;
}

static __device__ __forceinline__ unsigned short bbits(bf16_t v) {
  union { bf16_t b; unsigned short u; } c; c.b = v; return c.u;
}

// A-panel LDS geometry: [64 rows][264 bf16] (pad 8 -> 528B row, bank-balanced)
#define APITCH 264
#define ABYTES (64 * APITCH * 2)   // 33792

// ---- weight transpose + bf16 convert: Wt[n][k] = bf16(W[k][n]), 4 matrices ----
__global__ __launch_bounds__(256)
void prep_weights(const float* __restrict__ Wq, const float* __restrict__ Wk,
                  const float* __restrict__ Wv, const float* __restrict__ Wo,
                  bf16_t* __restrict__ wt) {
  const int mat  = blockIdx.x >> 6;
  const int tile = blockIdx.x & 63;
  const int kt = (tile >> 3) * 32, nt = (tile & 7) * 32;
  const float* W = (mat == 0) ? Wq : (mat == 1) ? Wk : (mat == 2) ? Wv : Wo;
  __shared__ float t[32][33];
  const int tx = threadIdx.x & 31, ty = threadIdx.x >> 5;  // ty 0..7
#pragma unroll
  for (int i = 0; i < 32; i += 8)
    t[ty + i][tx] = W[(size_t)(kt + ty + i) * 256 + nt + tx];
  __syncthreads();
  bf16_t* dst = wt + (size_t)mat * 65536;
#pragma unroll
  for (int i = 0; i < 32; i += 8)
    dst[(size_t)(nt + ty + i) * 256 + kt + tx] = (bf16_t)t[tx][ty + i];
}

// ---- merged projection GEMM: [M x 256] x [256 x 256] + bias ----
// grid (mblk, 3); mode = blockIdx.y: 0 -> qb (row-major, *qscale),
// 1 -> kb (rows b*4064+t+50, + left-pad replicate), 2 -> vt (transposed,
// + left-pad replicate). Block: 64 rows x 256 cols, 4 waves (n-slices).
__global__ __launch_bounds__(256)
void proj_gemm(const float* __restrict__ qx, const float* __restrict__ kx,
               const float* __restrict__ vx, const bf16_t* __restrict__ wt,
               const float* __restrict__ bq, const float* __restrict__ bk,
               const float* __restrict__ bv,
               bf16_t* __restrict__ qb, bf16_t* __restrict__ kb,
               bf16_t* __restrict__ vt, int M, float qscale) {
  const int mode = blockIdx.y;
  const float* X    = (mode == 0) ? qx : (mode == 1) ? kx : vx;
  const float* bias = (mode == 0) ? bq : (mode == 1) ? bk : bv;
  const bf16_t* W   = wt + (size_t)mode * 65536;

  __shared__ __align__(16) char lds[ABYTES + 2 * 16384];
  bf16_t* laA = (bf16_t*)lds;          // [64][264]
  char*   ldsB = lds + ABYTES;         // 2 x 16KB dbuf

  const int tid  = threadIdx.x;
  const int lane = tid & 63;
  const int w    = tid >> 6;           // wave 0..3 (n-slice wn = w*64)
  const int lo   = lane & 15, hi = lane >> 4;
  const int m0   = blockIdx.x * 64;

  // ---- stage WHOLE A panel (64KB fp32, contiguous 4KB per instruction) ----
  {
    const int colq = (tid & 63) * 4;   // fp32 col
    const int r0   = tid >> 6;
#pragma unroll
    for (int u = 0; u < 16; ++u) {
      const int r = r0 + u * 4;
      int ar = m0 + r; if (ar >= M) ar = M - 1;
      const float4 v = *(const float4*)(X + (size_t)ar * 256 + colq);
      *(bf16x4*)&laA[r * APITCH + colq] = cvt4(v);
    }
  }

  // ---- B staging sources (4 gloads/wave/tile; linear LDS slots) ----
  const bf16_t* bsrc[4];
  int boff[4];
#pragma unroll
  for (int j = 0; j < 4; ++j) {
    const int s = (w * 4 + j) * 64 + lane;  // slot 0..1023: row=s>>2, ch=s&3
    bsrc[j] = W + (size_t)(s >> 2) * 256 + ((s & 3) << 3);
    boff[j] = (w * 4 + j) * 1024;
  }
  int bbase[4];
#pragma unroll
  for (int ni = 0; ni < 4; ++ni)
    bbase[ni] = (w * 64 + ni * 16 + lo) * 64 + hi * 16;

  // issue B tile 0, then one full drain (also covers the A ds_writes)
#pragma unroll
  for (int j = 0; j < 4; ++j) gload16(bsrc[j], ldsB + boff[j]);
  __syncthreads();

  f32x4 acc[4][4] = {};

  for (int t = 0; t < 8; ++t) {
    const int cur = (t & 1) * 16384;
    if (t < 7) {
      const int nxt = ((t + 1) & 1) * 16384;
#pragma unroll
      for (int j = 0; j < 4; ++j) gload16(bsrc[j] + (t + 1) * 32, ldsB + nxt + boff[j]);
      asm volatile("s_waitcnt vmcnt(4)" ::: "memory");  // tile t landed
    } else {
      asm volatile("s_waitcnt vmcnt(0)" ::: "memory");
    }
    __builtin_amdgcn_sched_barrier(0);
    __builtin_amdgcn_s_barrier();

    bf16x8 af[4], bfv[4];
#pragma unroll
    for (int mi = 0; mi < 4; ++mi)
      af[mi] = *(const bf16x8*)&laA[(mi * 16 + lo) * APITCH + t * 32 + hi * 8];
#pragma unroll
    for (int ni = 0; ni < 4; ++ni)
      bfv[ni] = *(const bf16x8*)(ldsB + cur + bbase[ni]);
#pragma unroll
    for (int mi = 0; mi < 4; ++mi)
#pragma unroll
      for (int ni = 0; ni < 4; ++ni)
        acc[mi][ni] = MFMA16(af[mi], bfv[ni], acc[mi][ni]);
    __builtin_amdgcn_sched_barrier(0);
    __builtin_amdgcn_s_barrier();      // buf[cur] free for t+2's issue
  }

  // epilogue: C/D layout col = lane&15, row = (lane>>4)*4 + r  [m89-verified]
#pragma unroll
  for (int mi = 0; mi < 4; ++mi) {
    const int mb = m0 + mi * 16 + hi * 4;   // 4-aligned; M % 4 == 0
    if (mb >= M) continue;
#pragma unroll
    for (int ni = 0; ni < 4; ++ni) {
      const int n = w * 64 + ni * 16 + lo;
      const float bia = bias[n];
      if (mode == 0) {
#pragma unroll
        for (int rr = 0; rr < 4; ++rr)
          qb[(size_t)(mb + rr) * 256 + n] = (bf16_t)((acc[mi][ni][rr] + bia) * qscale);
      } else if (mode == 1) {
        const int b = mb / 4000, t = mb - b * 4000;
#pragma unroll
        for (int rr = 0; rr < 4; ++rr) {
          const bf16_t v = (bf16_t)(acc[mi][ni][rr] + bia);
          kb[((size_t)b * 4064 + t + 50 + rr) * 256 + n] = v;
          if (t == 0 && rr == 0)               // replicate left pad p<50
            for (int p = 0; p < 50; ++p)
              kb[((size_t)b * 4064 + p) * 256 + n] = v;
        }
      } else {
        const int b = mb / 4000, t = mb - b * 4000;
        const int h = n >> 5, dv = n & 31;
        const size_t vrow = ((size_t)((b * 8 + h) * 32 + dv)) * 4064;
        unsigned short e0 = bbits((bf16_t)(acc[mi][ni][0] + bia));
        unsigned short e1 = bbits((bf16_t)(acc[mi][ni][1] + bia));
        unsigned short e2 = bbits((bf16_t)(acc[mi][ni][2] + bia));
        unsigned short e3 = bbits((bf16_t)(acc[mi][ni][3] + bia));
        unsigned* O32 = (unsigned*)(vt + vrow + t + 50);  // (t+50) even
        O32[0] = (unsigned)e0 | ((unsigned)e1 << 16);
        O32[1] = (unsigned)e2 | ((unsigned)e3 << 16);
        if (t == 0) {                          // replicate left pad p<50
          const unsigned vv = (unsigned)e0 | ((unsigned)e0 << 16);
          unsigned* P = (unsigned*)(vt + vrow);
#pragma unroll
          for (int p = 0; p < 25; ++p) P[p] = vv;
        }
      }
    }
  }
}

// ---- output GEMM: ao[M x 256] (bf16) x Wo^T + bo -> fp32 out ----
__global__ __launch_bounds__(256)
void out_gemm(const bf16_t* __restrict__ ao, const bf16_t* __restrict__ wt,
              const float* __restrict__ bias, float* __restrict__ Out, int M) {
  __shared__ __align__(16) char lds[ABYTES + 2 * 16384];
  bf16_t* laA = (bf16_t*)lds;
  char*   ldsB = lds + ABYTES;

  const int tid  = threadIdx.x;
  const int lane = tid & 63;
  const int w    = tid >> 6;
  const int lo   = lane & 15, hi = lane >> 4;
  const int m0   = blockIdx.x * 64;

  // stage whole A panel (32KB bf16, contiguous 4KB per instruction)
  {
    const int colb = (tid & 31) * 8;   // bf16 col
    const int r0   = tid >> 5;
#pragma unroll
    for (int u = 0; u < 8; ++u) {
      const int r = r0 + u * 8;
      int ar = m0 + r; if (ar >= M) ar = M - 1;
      const bf16x8 v = *(const bf16x8*)(ao + (size_t)ar * 256 + colb);
      *(bf16x8*)&laA[r * APITCH + colb] = v;
    }
  }

  const bf16_t* bsrc[4];
  int boff[4];
#pragma unroll
  for (int j = 0; j < 4; ++j) {
    const int s = (w * 4 + j) * 64 + lane;
    bsrc[j] = wt + (size_t)(s >> 2) * 256 + ((s & 3) << 3);
    boff[j] = (w * 4 + j) * 1024;
  }
  int bbase[4];
#pragma unroll
  for (int ni = 0; ni < 4; ++ni)
    bbase[ni] = (w * 64 + ni * 16 + lo) * 64 + hi * 16;

#pragma unroll
  for (int j = 0; j < 4; ++j) gload16(bsrc[j], ldsB + boff[j]);
  __syncthreads();

  f32x4 acc[4][4] = {};

  for (int t = 0; t < 8; ++t) {
    const int cur = (t & 1) * 16384;
    if (t < 7) {
      const int nxt = ((t + 1) & 1) * 16384;
#pragma unroll
      for (int j = 0; j < 4; ++j) gload16(bsrc[j] + (t + 1) * 32, ldsB + nxt + boff[j]);
      asm volatile("s_waitcnt vmcnt(4)" ::: "memory");
    } else {
      asm volatile("s_waitcnt vmcnt(0)" ::: "memory");
    }
    __builtin_amdgcn_sched_barrier(0);
    __builtin_amdgcn_s_barrier();

    bf16x8 af[4], bfv[4];
#pragma unroll
    for (int mi = 0; mi < 4; ++mi)
      af[mi] = *(const bf16x8*)&laA[(mi * 16 + lo) * APITCH + t * 32 + hi * 8];
#pragma unroll
    for (int ni = 0; ni < 4; ++ni)
      bfv[ni] = *(const bf16x8*)(ldsB + cur + bbase[ni]);
#pragma unroll
    for (int mi = 0; mi < 4; ++mi)
#pragma unroll
      for (int ni = 0; ni < 4; ++ni)
        acc[mi][ni] = MFMA16(af[mi], bfv[ni], acc[mi][ni]);
    __builtin_amdgcn_sched_barrier(0);
    __builtin_amdgcn_s_barrier();
  }

#pragma unroll
  for (int mi = 0; mi < 4; ++mi) {
    const int mb = m0 + mi * 16 + hi * 4;
    if (mb >= M) continue;
#pragma unroll
    for (int ni = 0; ni < 4; ++ni) {
      const int n = w * 64 + ni * 16 + lo;
      const float bia = bias[n];
#pragma unroll
      for (int rr = 0; rr < 4; ++rr)
        Out[(size_t)(mb + rr) * 256 + n] = acc[mi][ni][rr] + bia;
    }
  }
}

// ---- windowed attention: one block per (b',h,window), 7 waves = 7 row-strips ----
// Chunked: per 32-col chunk {2x QK MFMA -> exp -> 16x32 LDS bounce -> PV 3 MFMA}.
// No cross-lane ops, no barriers; denom via E@ones; normalize after PV.
// kb/vt beyond p=4049 are unwritten garbage — those j's are causally masked
// (E set to exact 0), and 0 * finite-garbage = 0, so PV/denominator are exact.
__global__ __launch_bounds__(448)
void attn_win(const bf16_t* __restrict__ qb, const bf16_t* __restrict__ kb,
              const bf16_t* __restrict__ vt, bf16_t* __restrict__ ao) {
  const int blk = blockIdx.x;
  const int n = blk % 40;
  const int h = (blk / 40) & 7;
  const int b = blk / 320;
  const int wv = threadIdx.x >> 6;     // strip 0..6, rows i in [50+16wv, 66+16wv)
  const int lane = threadIdx.x & 63;
  const int lo = lane & 15, hi = lane >> 4;

  __shared__ __align__(16) bf16_t E[7][16][40];  // per-wave 16x32 chunk (pad 40)

  const int i0 = 50 + 16 * wv;
  int jtmax = (65 + 16 * wv) >> 4;     // last 16-tile with any unmasked element
  if (jtmax > 9) jtmax = 9;
  const int reach = jtmax * 16 + 16;

  // Q fragment (pre-scaled by 1/sqrt(200)): row lo -> token t = n*100+16wv+lo
  int tq = n * 100 + 16 * wv + lo;
  if (tq > 3999) tq = 3999;            // rows i>=150 are discarded at store
  const bf16x8 qf = *(const bf16x8*)&qb[((size_t)b * 4000 + tq) * 256 + h * 32 + hi * 8];

  const f32x4 zero = {0.f, 0.f, 0.f, 0.f};
  bf16x8 onesf;
#pragma unroll
  for (int u = 0; u < 8; ++u) onesf[u] = (bf16_t)1.0f;

  f32x4 o0 = zero, o1 = zero, sm = zero;
  const size_t vbase = ((size_t)((b * 8 + h) * 32)) * 4064 + n * 100;
  const size_t kbase = ((size_t)(b * 4064 + n * 100)) * 256 + h * 32 + hi * 8;
  const int dbase = i0 + hi * 4 - lo;  // d = dbase + r - 16*jt

#pragma unroll
  for (int kt = 0; kt < 5; ++kt) if (kt * 32 < reach) {
    // two score tiles -> E chunk [16][32]
#pragma unroll
    for (int half = 0; half < 2; ++half) {
      const int jt = kt * 2 + half;
      if (jt <= jtmax) {
        const bf16x8 kf = *(const bf16x8*)&kb[kbase + (size_t)(jt * 16 + lo) * 256];
        const f32x4 s = MFMA16(qf, kf, zero);
#pragma unroll
        for (int r = 0; r < 4; ++r) {
          const int d = dbase + r - jt * 16;
          const float df = (float)d;
          float c = __builtin_amdgcn_rcpf(__builtin_fmaf(0.25f * df, df, 1.f));
          c = (d == 0) ? 0.f : c;      // eye-mask: diagonal score -> 0 -> e=1
          float e = __expf(s[r] * c);
          e = (d < 0) ? 0.f : e;       // causal mask (also kills garbage-K j's)
          E[wv][hi * 4 + r][half * 16 + lo] = (bf16_t)e;
        }
      } else {
#pragma unroll
        for (int r = 0; r < 4; ++r)
          E[wv][hi * 4 + r][half * 16 + lo] = (bf16_t)0.f;
      }
    }
    // PV + denom for this 32-col chunk (wave-private LDS, in-order DS)
    const bf16x8 pf = *(const bf16x8*)&E[wv][lo][hi * 8];
    const bf16x8 v0 = *(const bf16x8*)&vt[vbase + (size_t)lo * 4064 + kt * 32 + hi * 8];
    const bf16x8 v1 = *(const bf16x8*)&vt[vbase + (size_t)(16 + lo) * 4064 + kt * 32 + hi * 8];
    o0 = MFMA16(pf, v0, o0);
    o1 = MFMA16(pf, v1, o1);
    sm = MFMA16(pf, onesf, sm);
  }

  // store central rows (i in [50,150)): out = o * rcp(rowsum); rowsum >= 1
#pragma unroll
  for (int r = 0; r < 4; ++r) {
    const int i = i0 + hi * 4 + r;
    if (i < 150) {
      const float ri = __builtin_amdgcn_rcpf(sm[r]);
      const int t = n * 100 + i - 50;
      bf16_t* op = &ao[((size_t)b * 4000 + t) * 256 + h * 32];
      op[lo]      = (bf16_t)(o0[r] * ri);
      op[16 + lo] = (bf16_t)(o1[r] * ri);
    }
  }
}

// ---------------------------------------------------------------------------
extern "C" void kernel_launch(void* const* d_in, const int* in_sizes, int n_in,
                              void* d_out, int out_size, void* d_ws, size_t ws_size,
                              hipStream_t stream) {
  (void)in_sizes; (void)n_in; (void)out_size;
  const float* query = (const float*)d_in[0];
  const float* key   = (const float*)d_in[1];
  const float* value = (const float*)d_in[2];
  const float* Wq = (const float*)d_in[3];
  const float* bq = (const float*)d_in[4];
  const float* Wk = (const float*)d_in[5];
  const float* bk = (const float*)d_in[6];
  const float* Wv = (const float*)d_in[7];
  const float* bv = (const float*)d_in[8];
  const float* Wo = (const float*)d_in[9];
  const float* bo = (const float*)d_in[10];

  // batch chunk (ws is large enough for bc=8 in practice)
  int bc = 8;
  while (bc > 1 && 524288ull + (unsigned long long)bc * 8257536ull > (unsigned long long)ws_size)
    bc >>= 1;

  bf16_t* wt = (bf16_t*)d_ws;                           // 4 * 65536
  bf16_t* qb = wt + 4 * 65536;                          // bc*4000*256
  bf16_t* kb = qb + (size_t)bc * 4000 * 256;            // bc*4064*256
  bf16_t* vt = kb + (size_t)bc * 4064 * 256;            // bc*8*32*4064
  bf16_t* ao = vt + (size_t)bc * 8 * 32 * 4064;         // bc*4000*256

  prep_weights<<<256, 256, 0, stream>>>(Wq, Wk, Wv, Wo, wt);

  const float qscale = 0.07071067811865475f;  // 1/sqrt(200) folded into qb

  for (int b0 = 0; b0 < 8; b0 += bc) {
    const int M = bc * 4000;
    const int mblk = (M + 63) / 64;
    const float* qx = query + (size_t)b0 * 4000 * 256;
    const float* kx = key   + (size_t)b0 * 4000 * 256;
    const float* vx = value + (size_t)b0 * 4000 * 256;
    float* ox = (float*)d_out + (size_t)b0 * 4000 * 256;

    proj_gemm<<<dim3(mblk, 3), 256, 0, stream>>>(qx, kx, vx, wt, bq, bk, bv,
                                                 qb, kb, vt, M, qscale);
    attn_win<<<bc * 320, 448, 0, stream>>>(qb, kb, vt, ao);
    out_gemm<<<dim3(mblk), 256, 0, stream>>>(ao, wt + 3 * 65536, bo, ox, M);
  }
}